// Round 1
// baseline (760.658 us; speedup 1.0000x reference)
//
#include <hip/hip_runtime.h>

#define B_  2
#define C_  256
#define S_  6272
#define P_  128
#define NS_ 5
#define KS_ 7
#define KCH_ 896
#define EPS_ 1e-5f

typedef __attribute__((ext_vector_type(8))) short short8;
typedef __attribute__((ext_vector_type(4))) float f32x4;

__device__ __forceinline__ ushort f2bf(float f) {
    union { float f; unsigned u; } v; v.f = f;
    unsigned r = v.u + 0x7fffu + ((v.u >> 16) & 1u);
    return (ushort)(r >> 16);
}
__device__ __forceinline__ float bf2f(ushort h) {
    union { unsigned u; float f; } v; v.u = ((unsigned)h) << 16;
    return v.f;
}

// ---------------------------------------------------------------------------
// Weight conversion: Wt,Wp,Wg -> bf16 direct [P,C]; cat[i][c][k] = [W1|W2]
// ---------------------------------------------------------------------------
__global__ void k_convert_weights(const float* __restrict__ Wt, const float* __restrict__ Wp,
                                  const float* __restrict__ Wg, const float* __restrict__ W1,
                                  const float* __restrict__ W2,
                                  ushort* __restrict__ Wtb, ushort* __restrict__ Wpb,
                                  ushort* __restrict__ Wgb, ushort* __restrict__ catb) {
    int i = blockIdx.x * 256 + threadIdx.x;
    const int nWt  = P_ * C_;            // 32768
    const int nWg  = NS_ * P_ * C_;      // 163840
    const int nCat = NS_ * C_ * 2 * P_;  // 327680
    if (i < nWt) { Wtb[i] = f2bf(Wt[i]); Wpb[i] = f2bf(Wp[i]); }
    if (i < nWg) { Wgb[i] = f2bf(Wg[i]); }
    if (i < nCat) {
        int k  = i & 255;
        int c  = (i >> 8) & (C_ - 1);
        int st = i >> 16;
        float v = (k < P_) ? W1[((size_t)st * C_ + c) * P_ + k]
                           : W2[((size_t)st * C_ + c) * P_ + (k - P_)];
        catb[i] = f2bf(v);
    }
}

// ---------------------------------------------------------------------------
// init: out = x (fp32 copy), xb_sc[b][s][c] = bf16(x[b][c][s])
// ---------------------------------------------------------------------------
__global__ void k_init_x(const float* __restrict__ x, float* __restrict__ out,
                         ushort* __restrict__ xb_sc) {
    int bc = blockIdx.x;            // b*C_ + c
    int b = bc / C_, c = bc - b * C_;
    const float* xr = x + (long)bc * S_;
    float* orow = out + (long)bc * S_;
    ushort* xs = xb_sc + (long)b * S_ * C_;
    for (int s = threadIdx.x; s < S_; s += 256) {
        float v = xr[s];
        orow[s] = v;
        xs[(long)s * C_ + c] = f2bf(v);
    }
}

// ---------------------------------------------------------------------------
// NT GEMM: Out[M,N] = A[M,K] * B[N,K]^T   (both operands K-contiguous bf16)
// MODE 0: bf16 Out;  MODE 1: bf16 Out + bf16 OutT[N,M];  MODE 2: fp32 Out
// Split-K via nks/kch: z = b*nks + chunk; Out offset z*sO.
// 128x128 tile, 4 waves (each 64x64 = 4x4 frags of 16x16), BK=32.
// ---------------------------------------------------------------------------
template <int MODE>
__global__ __launch_bounds__(256, 2)
void k_gemm(const ushort* __restrict__ A, const ushort* __restrict__ Bm,
            void* __restrict__ Out, ushort* __restrict__ OutT,
            int M, int N, int K, int lda, int ldb, int ldo, int ldot,
            long sA, long sB, long sO, long sOT, int nks, int kch) {
    const int z = blockIdx.z;
    const int b = z / nks, ch = z - b * nks;
    A  += (long)b * sA;
    Bm += (long)b * sB;
    const int k0 = ch * kch, k1 = k0 + kch;

    const int bm = blockIdx.x * 128, bn = blockIdx.y * 128;

    __shared__ ushort Al[128][40];  // [row][k] padded: 80B rows, b128-aligned
    __shared__ ushort Bl[128][40];

    const int tid = threadIdx.x, lane = tid & 63, wid = tid >> 6;
    const int wr = (wid >> 1) * 64, wc = (wid & 1) * 64;
    const int r16 = lane & 15, kg = lane >> 4;

    f32x4 acc[4][4];
    #pragma unroll
    for (int i = 0; i < 4; ++i)
        #pragma unroll
        for (int j = 0; j < 4; ++j)
            acc[i][j] = (f32x4){0.f, 0.f, 0.f, 0.f};

    for (int kk = k0; kk < k1; kk += 32) {
        // stage A tile: 128 rows x 32 k (512 units of 8 bf16; 2 per thread)
        {
            int u = tid;         int r = u >> 2, c8 = (u & 3) << 3;
            *(short8*)&Al[r][c8] = *(const short8*)&A[(long)(bm + r) * lda + kk + c8];
        }
        {
            int u = tid + 256;   int r = u >> 2, c8 = (u & 3) << 3;
            *(short8*)&Al[r][c8] = *(const short8*)&A[(long)(bm + r) * lda + kk + c8];
        }
        {
            int u = tid;         int r = u >> 2, c8 = (u & 3) << 3;
            *(short8*)&Bl[r][c8] = *(const short8*)&Bm[(long)(bn + r) * ldb + kk + c8];
        }
        {
            int u = tid + 256;   int r = u >> 2, c8 = (u & 3) << 3;
            *(short8*)&Bl[r][c8] = *(const short8*)&Bm[(long)(bn + r) * ldb + kk + c8];
        }
        __syncthreads();

        short8 af[4], bfv[4];
        #pragma unroll
        for (int i = 0; i < 4; ++i)
            af[i] = *(const short8*)&Al[wr + i * 16 + r16][kg * 8];
        #pragma unroll
        for (int j = 0; j < 4; ++j)
            bfv[j] = *(const short8*)&Bl[wc + j * 16 + r16][kg * 8];

        #pragma unroll
        for (int i = 0; i < 4; ++i)
            #pragma unroll
            for (int j = 0; j < 4; ++j)
                acc[i][j] = __builtin_amdgcn_mfma_f32_16x16x32_bf16(af[i], bfv[j], acc[i][j], 0, 0, 0);
        __syncthreads();
    }

    const int orow0 = bm + wr + kg * 4;
    const int ocol0 = bn + wc + r16;
    if (MODE == 2) {
        float* O = (float*)Out + (long)z * sO;
        #pragma unroll
        for (int i = 0; i < 4; ++i)
            #pragma unroll
            for (int j = 0; j < 4; ++j)
                #pragma unroll
                for (int q = 0; q < 4; ++q)
                    O[(long)(orow0 + i * 16 + q) * ldo + (ocol0 + j * 16)] = acc[i][j][q];
    } else {
        ushort* O = (ushort*)Out + (long)z * sO;
        ushort* OT = (MODE == 1) ? (OutT + (long)z * sOT) : nullptr;
        #pragma unroll
        for (int i = 0; i < 4; ++i)
            #pragma unroll
            for (int j = 0; j < 4; ++j)
                #pragma unroll
                for (int q = 0; q < 4; ++q) {
                    ushort h = f2bf(acc[i][j][q]);
                    O[(long)(orow0 + i * 16 + q) * ldo + (ocol0 + j * 16)] = h;
                    if (MODE == 1)
                        OT[(long)(ocol0 + j * 16) * ldot + (orow0 + i * 16 + q)] = h;
                }
    }
}

// ---------------------------------------------------------------------------
// In-place row softmax over bf16 scores: B_*S_ rows of length S_
// ---------------------------------------------------------------------------
__global__ __launch_bounds__(256)
void k_softmax(ushort* __restrict__ att) {
    long row = blockIdx.x;
    ushort* r = att + row * (long)S_;
    const int tid = threadIdx.x;
    __shared__ float red1[4];
    __shared__ float red2[4];

    float v[25];
    float mx = -1e30f;
    #pragma unroll
    for (int i = 0; i < 25; ++i) {
        int idx = i * 256 + tid;
        float xv = (idx < S_) ? bf2f(r[idx]) : -1e30f;
        v[i] = xv;
        mx = fmaxf(mx, xv);
    }
    #pragma unroll
    for (int off = 32; off; off >>= 1) mx = fmaxf(mx, __shfl_xor(mx, off));
    if ((tid & 63) == 0) red1[tid >> 6] = mx;
    __syncthreads();
    mx = fmaxf(fmaxf(red1[0], red1[1]), fmaxf(red1[2], red1[3]));

    float sum = 0.f;
    #pragma unroll
    for (int i = 0; i < 25; ++i) {
        int idx = i * 256 + tid;
        float e = (idx < S_) ? __expf(v[i] - mx) : 0.f;
        v[i] = e;
        sum += e;
    }
    #pragma unroll
    for (int off = 32; off; off >>= 1) sum += __shfl_xor(sum, off);
    if ((tid & 63) == 0) red2[tid >> 6] = sum;
    __syncthreads();
    sum = red2[0] + red2[1] + red2[2] + red2[3];
    float inv = 1.f / sum;

    #pragma unroll
    for (int i = 0; i < 25; ++i) {
        int idx = i * 256 + tid;
        if (idx < S_) r[idx] = f2bf(v[i] * inv);
    }
}

// ---------------------------------------------------------------------------
// Reduce split-K buffer -> BcatT[b][s][128+p] (bf16)
// split layout: [b][ch][s][p] fp32
// ---------------------------------------------------------------------------
__global__ void k_reduce_split(const float* __restrict__ split, ushort* __restrict__ BcatT) {
    long i = (long)blockIdx.x * 256 + threadIdx.x;   // over B_*S_*P_
    if (i >= (long)B_ * S_ * P_) return;
    int p = (int)(i & (P_ - 1));
    long sp = i >> 7;                                 // b*S_ + s
    int b = (int)(sp / S_);
    long s = sp - (long)b * S_;
    const float* base = split + (long)b * KS_ * S_ * P_ + s * P_ + p;
    float acc = 0.f;
    #pragma unroll
    for (int ch = 0; ch < KS_; ++ch) acc += base[(long)ch * S_ * P_];
    BcatT[((long)b * S_ + s) * 256 + 128 + p] = f2bf(acc);
}

// ---------------------------------------------------------------------------
// BN stats: per channel c over (b, s): mean + rsqrt(var+eps)
// ---------------------------------------------------------------------------
__global__ __launch_bounds__(256)
void k_bn_stats(const float* __restrict__ y, float* __restrict__ mu, float* __restrict__ rs) {
    int c = blockIdx.x;
    const int tid = threadIdx.x;
    float s1 = 0.f, s2 = 0.f;
    for (int b = 0; b < B_; ++b) {
        const float* r = y + ((long)b * C_ + c) * S_;
        for (int s = tid; s < S_; s += 256) {
            float v = r[s];
            s1 += v;
            s2 += v * v;
        }
    }
    #pragma unroll
    for (int off = 32; off; off >>= 1) {
        s1 += __shfl_xor(s1, off);
        s2 += __shfl_xor(s2, off);
    }
    __shared__ float a1[4], a2[4];
    if ((tid & 63) == 0) { a1[tid >> 6] = s1; a2[tid >> 6] = s2; }
    __syncthreads();
    if (tid == 0) {
        s1 = a1[0] + a1[1] + a1[2] + a1[3];
        s2 = a2[0] + a2[1] + a2[2] + a2[3];
        const float invn = 1.f / (float)(B_ * S_);
        float m = s1 * invn;
        float var = s2 * invn - m * m;
        mu[c] = m;
        rs[c] = rsqrtf(var + EPS_);
    }
}

// ---------------------------------------------------------------------------
// BN apply + residual: out += BN(y); also write xb_sc (bf16 transposed out)
// ---------------------------------------------------------------------------
__global__ __launch_bounds__(256)
void k_bn_apply(const float* __restrict__ y, const float* __restrict__ mu,
                const float* __restrict__ rs, const float* __restrict__ gamma,
                const float* __restrict__ beta, float* __restrict__ out,
                ushort* __restrict__ xb_sc) {
    int bc = blockIdx.x;
    int b = bc / C_, c = bc - b * C_;
    float m = mu[c], r = rs[c], g = gamma[c], be = beta[c];
    const float* yr = y + (long)bc * S_;
    float* orow = out + (long)bc * S_;
    ushort* xs = xb_sc + (long)b * S_ * C_;
    for (int s = threadIdx.x; s < S_; s += 256) {
        float v = orow[s] + (yr[s] - m) * r * g + be;
        orow[s] = v;
        xs[(long)s * C_ + c] = f2bf(v);
    }
}

// ---------------------------------------------------------------------------
extern "C" void kernel_launch(void* const* d_in, const int* in_sizes, int n_in,
                              void* d_out, int out_size, void* d_ws, size_t ws_size,
                              hipStream_t stream) {
    const float* x     = (const float*)d_in[0];
    const float* Wt    = (const float*)d_in[1];
    const float* Wp    = (const float*)d_in[2];
    const float* Wg    = (const float*)d_in[3];
    const float* W1    = (const float*)d_in[4];
    const float* W2    = (const float*)d_in[5];
    const float* gamma = (const float*)d_in[6];
    const float* beta  = (const float*)d_in[7];
    float* out = (float*)d_out;

    char* ws = (char*)d_ws;
    size_t off = 0;
    auto alloc = [&](size_t bytes) -> void* {
        void* p = ws + off;
        off = (off + bytes + 255) & ~(size_t)255;
        return p;
    };
    ushort* att   = (ushort*)alloc((size_t)B_ * S_ * S_ * 2);      // scores/att bf16
    ushort* tb    = (ushort*)alloc((size_t)B_ * S_ * P_ * 2);      // t   [S,P]
    ushort* ptb   = (ushort*)alloc((size_t)B_ * S_ * P_ * 2);      // p^T [S,P]
    ushort* gTb   = (ushort*)alloc((size_t)B_ * P_ * S_ * 2);      // g^T [P,S]
    ushort* BcatT = (ushort*)alloc((size_t)B_ * S_ * 256 * 2);     // [s][g | x2pre]
    ushort* xbsc  = (ushort*)alloc((size_t)B_ * S_ * C_ * 2);      // out^T bf16 [S,C]
    float*  y     = (float*)alloc((size_t)B_ * C_ * S_ * 4);       // x1+x2 fp32 [C,S]
    float*  split = (float*)alloc((size_t)B_ * KS_ * S_ * P_ * 4); // split-K buffer
    ushort* Wtb   = (ushort*)alloc((size_t)P_ * C_ * 2);
    ushort* Wpb   = (ushort*)alloc((size_t)P_ * C_ * 2);
    ushort* Wgb   = (ushort*)alloc((size_t)NS_ * P_ * C_ * 2);
    ushort* catb  = (ushort*)alloc((size_t)NS_ * C_ * 256 * 2);
    float*  mu    = (float*)alloc(C_ * 4);
    float*  rs    = (float*)alloc(C_ * 4);
    if (off > ws_size) return;  // workspace too small -> will show as validation failure

    dim3 blk(256);

    k_convert_weights<<<1280, 256, 0, stream>>>(Wt, Wp, Wg, W1, W2, Wtb, Wpb, Wgb, catb);
    k_init_x<<<B_ * C_, 256, 0, stream>>>(x, out, xbsc);

    // t = NT(xbsc[S,C], Wt[P,C]) -> tb [S,P]
    k_gemm<0><<<dim3(S_ / 128, P_ / 128, B_), blk, 0, stream>>>(
        xbsc, Wtb, tb, nullptr, S_, P_, C_, C_, C_, P_, 0,
        (long)S_ * C_, 0, (long)S_ * P_, 0, 1, C_);
    // p^T = NT(xbsc, Wp) -> ptb [S,P]
    k_gemm<0><<<dim3(S_ / 128, P_ / 128, B_), blk, 0, stream>>>(
        xbsc, Wpb, ptb, nullptr, S_, P_, C_, C_, C_, P_, 0,
        (long)S_ * C_, 0, (long)S_ * P_, 0, 1, C_);
    // scores = NT(tb[S,P], ptb[S,P]) -> att [S,S]
    k_gemm<0><<<dim3(S_ / 128, S_ / 128, B_), blk, 0, stream>>>(
        tb, ptb, att, nullptr, S_, S_, P_, P_, P_, S_, 0,
        (long)S_ * P_, (long)S_ * P_, (long)S_ * S_, 0, 1, P_);
    k_softmax<<<B_ * S_, 256, 0, stream>>>(att);

    for (int i = 0; i < NS_; ++i) {
        // g = NT(xbsc, Wg[i]) -> BcatT cols [0,128) (ldo=256) + gTb [P,S]
        k_gemm<1><<<dim3(S_ / 128, P_ / 128, B_), blk, 0, stream>>>(
            xbsc, Wgb + (size_t)i * P_ * C_, BcatT, gTb,
            S_, P_, C_, C_, C_, 256, S_,
            (long)S_ * C_, 0, (long)S_ * 256, (long)P_ * S_, 1, C_);
        // x2pre(split-K) = NT(att[S,S], gT[P,S]) -> split fp32
        k_gemm<2><<<dim3(S_ / 128, P_ / 128, B_ * KS_), blk, 0, stream>>>(
            att, gTb, split, nullptr, S_, P_, S_, S_, S_, P_, 0,
            (long)S_ * S_, (long)P_ * S_, (long)S_ * P_, 0, KS_, KCH_);
        k_reduce_split<<<(int)(((long)B_ * S_ * P_ + 255) / 256), 256, 0, stream>>>(split, BcatT);
        // y = NT(cat[i][C,256], BcatT[S,256]) -> [C,S] fp32
        k_gemm<2><<<dim3(C_ / 128, S_ / 128, B_), blk, 0, stream>>>(
            catb + (size_t)i * C_ * 256, BcatT, y, nullptr,
            C_, S_, 256, 256, 256, S_, 0,
            0, (long)S_ * 256, (long)C_ * S_, 0, 1, 256);
        k_bn_stats<<<C_, 256, 0, stream>>>(y, mu, rs);
        k_bn_apply<<<B_ * C_, 256, 0, stream>>>(y, mu, rs, gamma + i * C_, beta + i * C_, out, xbsc);
    }
}

// Round 3
// 729.434 us; speedup vs baseline: 1.0428x; 1.0428x over previous
//
#include <hip/hip_runtime.h>

#define B_  2
#define C_  256
#define S_  6272
#define P_  128
#define NS_ 5
#define KS_ 7
#define KCH_ 896
#define EPS_ 1e-5f

typedef __attribute__((ext_vector_type(8))) short short8;
typedef __attribute__((ext_vector_type(4))) float f32x4;

__device__ __forceinline__ ushort f2bf(float f) {
    union { float f; unsigned u; } v; v.f = f;
    unsigned r = v.u + 0x7fffu + ((v.u >> 16) & 1u);
    return (ushort)(r >> 16);
}
__device__ __forceinline__ float bf2f(ushort h) {
    union { unsigned u; float f; } v; v.u = ((unsigned)h) << 16;
    return v.f;
}

// async global->LDS, 16 bytes per lane; lds dest = wave-uniform base + lane*16
__device__ __forceinline__ void gload16(const ushort* g, ushort* lds) {
    __builtin_amdgcn_global_load_lds(
        (const __attribute__((address_space(1))) void*)g,
        (__attribute__((address_space(3))) void*)lds, 16, 0, 0);
}

// ---------------------------------------------------------------------------
// Weight conversion: Wtp = [Wt;Wp] bf16 [2P,C]; Wg bf16; cat[i][c][k]=[W1|W2]
// ---------------------------------------------------------------------------
__global__ void k_convert_weights(const float* __restrict__ Wt, const float* __restrict__ Wp,
                                  const float* __restrict__ Wg, const float* __restrict__ W1,
                                  const float* __restrict__ W2,
                                  ushort* __restrict__ Wtpb,
                                  ushort* __restrict__ Wgb, ushort* __restrict__ catb) {
    int i = blockIdx.x * 256 + threadIdx.x;
    const int nWtp = 2 * P_ * C_;        // 65536
    const int nWg  = NS_ * P_ * C_;      // 163840
    const int nCat = NS_ * C_ * 2 * P_;  // 327680
    if (i < nWtp) {
        int c = i & (C_ - 1), row = i >> 8;
        float v = (row < P_) ? Wt[row * C_ + c] : Wp[(row - P_) * C_ + c];
        Wtpb[i] = f2bf(v);
    }
    if (i < nWg) { Wgb[i] = f2bf(Wg[i]); }
    if (i < nCat) {
        int k  = i & 255;
        int c  = (i >> 8) & (C_ - 1);
        int st = i >> 16;
        float v = (k < P_) ? W1[((size_t)st * C_ + c) * P_ + k]
                           : W2[((size_t)st * C_ + c) * P_ + (k - P_)];
        catb[i] = f2bf(v);
    }
}

// ---------------------------------------------------------------------------
// init: out = x (fp32 copy), xb_sc[b][s][c] = bf16(x[b][c][s])
// ---------------------------------------------------------------------------
__global__ void k_init_x(const float* __restrict__ x, float* __restrict__ out,
                         ushort* __restrict__ xb_sc) {
    int bc = blockIdx.x;            // b*C_ + c
    int b = bc / C_, c = bc - b * C_;
    const float* xr = x + (long)bc * S_;
    float* orow = out + (long)bc * S_;
    ushort* xs = xb_sc + (long)b * S_ * C_;
    for (int s = threadIdx.x; s < S_; s += 256) {
        float v = xr[s];
        orow[s] = v;
        xs[(long)s * C_ + c] = f2bf(v);
    }
}

// ---------------------------------------------------------------------------
// NT GEMM: Out[M,N] = A[M,K] * B[N,K]^T   (both operands K-contiguous bf16)
// MODE 0: bf16 Out;  MODE 1: bf16 Out + bf16 OutT[N,M];  MODE 2: fp32 Out
// Split-K via nks/kch: z = b*nks + chunk; Out offset z*sO.
// 128x128 tile, 4 waves (each 64x64 = 4x4 frags of 16x16), BK=32.
// Staging: global_load_lds dwordx4, linear LDS [128][32] with XOR slot swizzle
// applied to BOTH the global source and the ds_read (rule: both-sides-or-neither).
// ---------------------------------------------------------------------------
template <int MODE>
__global__ __launch_bounds__(256, 2)
void k_gemm(const ushort* __restrict__ A, const ushort* __restrict__ Bm,
            void* __restrict__ Out, ushort* __restrict__ OutT,
            int M, int N, int K, int lda, int ldb, int ldo, int ldot,
            long sA, long sB, long sO, long sOT, int nks, int kch) {
    const int z = blockIdx.z;
    const int b = z / nks, ch = z - b * nks;
    A  += (long)b * sA;
    Bm += (long)b * sB;
    const int k0 = ch * kch, k1 = k0 + kch;

    const int bm = blockIdx.x * 128, bn = blockIdx.y * 128;

    __shared__ ushort Al[128][32];  // linear (global_load_lds needs contiguity)
    __shared__ ushort Bl[128][32];

    const int tid = threadIdx.x, lane = tid & 63, wid = tid >> 6;
    const int wr = (wid >> 1) * 64, wc = (wid & 1) * 64;
    const int r16 = lane & 15, kg = lane >> 4;

    // staging geometry: one instr covers 16 rows (lane l -> row l>>2, slot l&3)
    const int st_row = lane >> 2;                       // 0..15
    const int st_slot = lane & 3;                       // 16B slot within row
    const int st_gk8 = ((st_slot ^ ((st_row >> 1) & 3)) << 3);  // swizzled k-elem off
    // fragment read: swizzled slot for (row=...+r16, kslot=kg)
    const int sw8 = ((kg ^ ((r16 >> 1) & 3)) << 3);

    const ushort* Arow0 = A + (long)(bm + wid * 32 + st_row) * lda + st_gk8;
    const ushort* Arow1 = A + (long)(bm + wid * 32 + 16 + st_row) * lda + st_gk8;
    const ushort* Brow0 = Bm + (long)(bn + wid * 32 + st_row) * ldb + st_gk8;
    const ushort* Brow1 = Bm + (long)(bn + wid * 32 + 16 + st_row) * ldb + st_gk8;

    f32x4 acc[4][4];
    #pragma unroll
    for (int i = 0; i < 4; ++i)
        #pragma unroll
        for (int j = 0; j < 4; ++j)
            acc[i][j] = (f32x4){0.f, 0.f, 0.f, 0.f};

    for (int kk = k0; kk < k1; kk += 32) {
        gload16(Arow0 + kk, &Al[wid * 32][0]);
        gload16(Arow1 + kk, &Al[wid * 32 + 16][0]);
        gload16(Brow0 + kk, &Bl[wid * 32][0]);
        gload16(Brow1 + kk, &Bl[wid * 32 + 16][0]);
        __syncthreads();

        short8 af[4], bfv[4];
        #pragma unroll
        for (int i = 0; i < 4; ++i)
            af[i] = *(const short8*)&Al[wr + i * 16 + r16][sw8];
        #pragma unroll
        for (int j = 0; j < 4; ++j)
            bfv[j] = *(const short8*)&Bl[wc + j * 16 + r16][sw8];

        #pragma unroll
        for (int i = 0; i < 4; ++i)
            #pragma unroll
            for (int j = 0; j < 4; ++j)
                acc[i][j] = __builtin_amdgcn_mfma_f32_16x16x32_bf16(af[i], bfv[j], acc[i][j], 0, 0, 0);
        __syncthreads();
    }

    const int orow0 = bm + wr + kg * 4;
    const int ocol0 = bn + wc + r16;
    if (MODE == 2) {
        float* O = (float*)Out + (long)z * sO;
        #pragma unroll
        for (int i = 0; i < 4; ++i)
            #pragma unroll
            for (int j = 0; j < 4; ++j)
                #pragma unroll
                for (int q = 0; q < 4; ++q)
                    O[(long)(orow0 + i * 16 + q) * ldo + (ocol0 + j * 16)] = acc[i][j][q];
    } else {
        ushort* O = (ushort*)Out + (long)z * sO;
        ushort* OT = (MODE == 1) ? (OutT + (long)z * sOT) : nullptr;
        #pragma unroll
        for (int i = 0; i < 4; ++i)
            #pragma unroll
            for (int j = 0; j < 4; ++j)
                #pragma unroll
                for (int q = 0; q < 4; ++q) {
                    ushort h = f2bf(acc[i][j][q]);
                    O[(long)(orow0 + i * 16 + q) * ldo + (ocol0 + j * 16)] = h;
                    if (MODE == 1)
                        OT[(long)(ocol0 + j * 16) * ldot + (orow0 + i * 16 + q)] = h;
                }
    }
}

// ---------------------------------------------------------------------------
// In-place row softmax over bf16 scores: B_*S_ rows of length S_ (vectorized)
// 6272 = 3*2048 + 128: threads 0..255 take short8 units {t, 256+t, 512+t},
// threads 0..15 additionally take unit 768+t.
// ---------------------------------------------------------------------------
__global__ __launch_bounds__(256)
void k_softmax(ushort* __restrict__ att) {
    long row = blockIdx.x;
    ushort* r = att + row * (long)S_;
    const int tid = threadIdx.x;
    __shared__ float red1[4];
    __shared__ float red2[4];
    const bool tail = tid < 16;

    short8 u0 = *(const short8*)&r[(0 * 256 + tid) * 8];
    short8 u1 = *(const short8*)&r[(1 * 256 + tid) * 8];
    short8 u2 = *(const short8*)&r[(2 * 256 + tid) * 8];
    short8 u3 = tail ? *(const short8*)&r[(768 + tid) * 8] : short8{0,0,0,0,0,0,0,0};

    float v[32];
    #pragma unroll
    for (int j = 0; j < 8; ++j) {
        v[j]      = bf2f((ushort)u0[j]);
        v[8 + j]  = bf2f((ushort)u1[j]);
        v[16 + j] = bf2f((ushort)u2[j]);
        v[24 + j] = tail ? bf2f((ushort)u3[j]) : -1e30f;
    }
    float mx = -1e30f;
    #pragma unroll
    for (int j = 0; j < 32; ++j) mx = fmaxf(mx, v[j]);
    #pragma unroll
    for (int off = 32; off; off >>= 1) mx = fmaxf(mx, __shfl_xor(mx, off));
    if ((tid & 63) == 0) red1[tid >> 6] = mx;
    __syncthreads();
    mx = fmaxf(fmaxf(red1[0], red1[1]), fmaxf(red1[2], red1[3]));

    float sum = 0.f;
    #pragma unroll
    for (int j = 0; j < 32; ++j) {
        float e = __expf(v[j] - mx);   // exp(-huge)=0 handles masked slots
        v[j] = e;
        sum += e;
    }
    #pragma unroll
    for (int off = 32; off; off >>= 1) sum += __shfl_xor(sum, off);
    if ((tid & 63) == 0) red2[tid >> 6] = sum;
    __syncthreads();
    sum = red2[0] + red2[1] + red2[2] + red2[3];
    float inv = 1.f / sum;

    short8 w0, w1, w2, w3;
    #pragma unroll
    for (int j = 0; j < 8; ++j) {
        w0[j] = (short)f2bf(v[j] * inv);
        w1[j] = (short)f2bf(v[8 + j] * inv);
        w2[j] = (short)f2bf(v[16 + j] * inv);
        w3[j] = (short)f2bf(v[24 + j] * inv);
    }
    *(short8*)&r[(0 * 256 + tid) * 8] = w0;
    *(short8*)&r[(1 * 256 + tid) * 8] = w1;
    *(short8*)&r[(2 * 256 + tid) * 8] = w2;
    if (tail) *(short8*)&r[(768 + tid) * 8] = w3;
}

// ---------------------------------------------------------------------------
// Reduce split-K buffer -> BcatT[b][s][128+p] (bf16)
// split layout: [b][ch][s][p] fp32
// ---------------------------------------------------------------------------
__global__ void k_reduce_split(const float* __restrict__ split, ushort* __restrict__ BcatT) {
    long i = (long)blockIdx.x * 256 + threadIdx.x;   // over B_*S_*P_
    if (i >= (long)B_ * S_ * P_) return;
    int p = (int)(i & (P_ - 1));
    long sp = i >> 7;                                 // b*S_ + s
    int b = (int)(sp / S_);
    long s = sp - (long)b * S_;
    const float* base = split + (long)b * KS_ * S_ * P_ + s * P_ + p;
    float acc = 0.f;
    #pragma unroll
    for (int ch = 0; ch < KS_; ++ch) acc += base[(long)ch * S_ * P_];
    BcatT[((long)b * S_ + s) * 256 + 128 + p] = f2bf(acc);
}

// ---------------------------------------------------------------------------
// BN stats: per channel c over (b, s): mean + rsqrt(var+eps)
// ---------------------------------------------------------------------------
__global__ __launch_bounds__(256)
void k_bn_stats(const float* __restrict__ y, float* __restrict__ mu, float* __restrict__ rs) {
    int c = blockIdx.x;
    const int tid = threadIdx.x;
    float s1 = 0.f, s2 = 0.f;
    for (int b = 0; b < B_; ++b) {
        const float* r = y + ((long)b * C_ + c) * S_;
        for (int s = tid; s < S_; s += 256) {
            float v = r[s];
            s1 += v;
            s2 += v * v;
        }
    }
    #pragma unroll
    for (int off = 32; off; off >>= 1) {
        s1 += __shfl_xor(s1, off);
        s2 += __shfl_xor(s2, off);
    }
    __shared__ float a1[4], a2[4];
    if ((tid & 63) == 0) { a1[tid >> 6] = s1; a2[tid >> 6] = s2; }
    __syncthreads();
    if (tid == 0) {
        s1 = a1[0] + a1[1] + a1[2] + a1[3];
        s2 = a2[0] + a2[1] + a2[2] + a2[3];
        const float invn = 1.f / (float)(B_ * S_);
        float m = s1 * invn;
        float var = s2 * invn - m * m;
        mu[c] = m;
        rs[c] = rsqrtf(var + EPS_);
    }
}

// ---------------------------------------------------------------------------
// BN apply + residual: out += BN(y); also write xb_sc (bf16 transposed out)
// ---------------------------------------------------------------------------
__global__ __launch_bounds__(256)
void k_bn_apply(const float* __restrict__ y, const float* __restrict__ mu,
                const float* __restrict__ rs, const float* __restrict__ gamma,
                const float* __restrict__ beta, float* __restrict__ out,
                ushort* __restrict__ xb_sc) {
    int bc = blockIdx.x;
    int b = bc / C_, c = bc - b * C_;
    float m = mu[c], r = rs[c], g = gamma[c], be = beta[c];
    const float* yr = y + (long)bc * S_;
    float* orow = out + (long)bc * S_;
    ushort* xs = xb_sc + (long)b * S_ * C_;
    for (int s = threadIdx.x; s < S_; s += 256) {
        float v = orow[s] + (yr[s] - m) * r * g + be;
        orow[s] = v;
        xs[(long)s * C_ + c] = f2bf(v);
    }
}

// ---------------------------------------------------------------------------
extern "C" void kernel_launch(void* const* d_in, const int* in_sizes, int n_in,
                              void* d_out, int out_size, void* d_ws, size_t ws_size,
                              hipStream_t stream) {
    const float* x     = (const float*)d_in[0];
    const float* Wt    = (const float*)d_in[1];
    const float* Wp    = (const float*)d_in[2];
    const float* Wg    = (const float*)d_in[3];
    const float* W1    = (const float*)d_in[4];
    const float* W2    = (const float*)d_in[5];
    const float* gamma = (const float*)d_in[6];
    const float* beta  = (const float*)d_in[7];
    float* out = (float*)d_out;

    char* ws = (char*)d_ws;
    size_t off = 0;
    auto alloc = [&](size_t bytes) -> void* {
        void* p = ws + off;
        off = (off + bytes + 255) & ~(size_t)255;
        return p;
    };
    ushort* att   = (ushort*)alloc((size_t)B_ * S_ * S_ * 2);      // scores/att bf16
    ushort* tpb   = (ushort*)alloc((size_t)B_ * S_ * 256 * 2);     // [s][t | p^T]
    ushort* gTb   = (ushort*)alloc((size_t)B_ * P_ * S_ * 2);      // g^T [P,S]
    ushort* BcatT = (ushort*)alloc((size_t)B_ * S_ * 256 * 2);     // [s][g | x2pre]
    ushort* xbsc  = (ushort*)alloc((size_t)B_ * S_ * C_ * 2);      // out^T bf16 [S,C]
    float*  y     = (float*)alloc((size_t)B_ * C_ * S_ * 4);       // x1+x2 fp32 [C,S]
    float*  split = (float*)alloc((size_t)B_ * KS_ * S_ * P_ * 4); // split-K buffer
    ushort* Wtpb  = (ushort*)alloc((size_t)2 * P_ * C_ * 2);
    ushort* Wgb   = (ushort*)alloc((size_t)NS_ * P_ * C_ * 2);
    ushort* catb  = (ushort*)alloc((size_t)NS_ * C_ * 256 * 2);
    float*  mu    = (float*)alloc(C_ * 4);
    float*  rs    = (float*)alloc(C_ * 4);
    if (off > ws_size) return;  // workspace too small -> will show as validation failure

    dim3 blk(256);

    k_convert_weights<<<1280, 256, 0, stream>>>(Wt, Wp, Wg, W1, W2, Wtpb, Wgb, catb);
    k_init_x<<<B_ * C_, 256, 0, stream>>>(x, out, xbsc);

    // [t | p^T] = NT(xbsc[S,C], Wtp[256,C]) -> tpb [S,256]
    k_gemm<0><<<dim3(S_ / 128, 2, B_), blk, 0, stream>>>(
        xbsc, Wtpb, tpb, nullptr, S_, 256, C_, C_, C_, 256, 0,
        (long)S_ * C_, 0, (long)S_ * 256, 0, 1, C_);
    // scores = NT(t[S,P] lda=256, p^T[S,P] ldb=256) -> att [S,S]
    k_gemm<0><<<dim3(S_ / 128, S_ / 128, B_), blk, 0, stream>>>(
        tpb, tpb + 128, att, nullptr, S_, S_, P_, 256, 256, S_, 0,
        (long)S_ * 256, (long)S_ * 256, (long)S_ * S_, 0, 1, P_);
    k_softmax<<<B_ * S_, 256, 0, stream>>>(att);

    for (int i = 0; i < NS_; ++i) {
        // g = NT(xbsc, Wg[i]) -> BcatT cols [0,128) (ldo=256) + gTb [P,S]
        k_gemm<1><<<dim3(S_ / 128, 1, B_), blk, 0, stream>>>(
            xbsc, Wgb + (size_t)i * P_ * C_, BcatT, gTb,
            S_, P_, C_, C_, C_, 256, S_,
            (long)S_ * C_, 0, (long)S_ * 256, (long)P_ * S_, 1, C_);
        // x2pre(split-K) = NT(att[S,S], gT[P,S]) -> split fp32
        k_gemm<2><<<dim3(S_ / 128, 1, B_ * KS_), blk, 0, stream>>>(
            att, gTb, split, nullptr, S_, P_, S_, S_, S_, P_, 0,
            (long)S_ * S_, (long)P_ * S_, (long)S_ * P_, 0, KS_, KCH_);
        k_reduce_split<<<(int)(((long)B_ * S_ * P_ + 255) / 256), 256, 0, stream>>>(split, BcatT);
        // y = NT(cat[i][C,256], BcatT[S,256]) -> [C,S] fp32
        k_gemm<2><<<dim3(C_ / 128, S_ / 128, B_), blk, 0, stream>>>(
            catb + (size_t)i * C_ * 256, BcatT, y, nullptr,
            C_, S_, 256, 256, 256, S_, 0,
            0, (long)S_ * 256, (long)C_ * S_, 0, 1, 256);
        k_bn_stats<<<C_, 256, 0, stream>>>(y, mu, rs);
        k_bn_apply<<<B_ * C_, 256, 0, stream>>>(y, mu, rs, gamma + i * C_, beta + i * C_, out, xbsc);
    }
}